// Round 5
// baseline (75.926 us; speedup 1.0000x reference)
//
#include <hip/hip_runtime.h>
#include <math.h>

// Fused SSIM: separable 11x11 gaussian depthwise conv of {x1,x2,x1^2,x2^2,x1*x2},
// SSIM map, global mean -> scalar. NCHW (16,3,512,512) fp32, VALID -> 502x502.
//
// R5 structure: block = 256 threads, each owns 2 adjacent columns (full 512-col
// width per block -> no column halo at all). Per row: 2 float2 global loads,
// 2 ds_write_b64, 12 ds_read_b64 (6 aligned b64 chunks per channel), shared
// per-position products, 110 h-FMA + 110 v-FMA for 2 pixels. Vertical via
// rotating 11-slot float2 window, all indices parse-time constants.
//   R0 lesson: dynamic acc indices -> scratch -> GBs of spill traffic.
//   R3 lesson: don't cap VGPR below live set -> launch_bounds(256,2).
//   R4 lesson: issue-bound per wave (~220 inst/px, 40% overhead) -> K=2
//     amortizes staging/addressing/barriers/LDS across 2 pixels.

#define W 512
#define H 512
#define OWID 502            // output rows/cols (512-11+1)
#define NS 16               // row strips
#define SH 32               // output rows per strip
#define NPLANES 48          // 16*3
#define NBLOCKS (NPLANES * NS)   // 768 = 3 blocks/CU
#define NTOTAL 12096192.0   // 48*502*502

// gaussian(sigma=1.5, ws=11), normalized; compile-time constants.
#define G0 0.00102838f
#define G1 0.00759860f
#define G2 0.03600090f
#define G3 0.10936100f
#define G4 0.21300540f
#define G5 0.26601170f
#define GW(K) (((K)==0||(K)==10) ? G0 : ((K)==1||(K)==9) ? G1 : \
               ((K)==2||(K)==8)  ? G2 : ((K)==3||(K)==7) ? G3 : \
               ((K)==4||(K)==6)  ? G4 : G5)

// horizontal position pp (literal 0..11): position col = 2*tid + pp.
// px0 (col 2t) uses taps pp=0..10 with GW(pp); px1 (col 2t+1) uses pp=1..11
// with GW(pp-1). Products shared between both pixels.
#define HPOS(pp) { \
    const float a_ = ((pp)&1) ? A[(pp)>>1].y : A[(pp)>>1].x; \
    const float b_ = ((pp)&1) ? B[(pp)>>1].y : B[(pp)>>1].x; \
    const float paa_ = a_*a_, pbb_ = b_*b_, pab_ = a_*b_; \
    if ((pp) < 11) { const float w_ = GW(pp); \
      h1.x  = fmaf(w_, a_,   h1.x);  h2.x  = fmaf(w_, b_,   h2.x); \
      h11.x = fmaf(w_, paa_, h11.x); h22.x = fmaf(w_, pbb_, h22.x); \
      h12.x = fmaf(w_, pab_, h12.x); } \
    if ((pp) >= 1) { const float w_ = GW((pp)-1); \
      h1.y  = fmaf(w_, a_,   h1.y);  h2.y  = fmaf(w_, b_,   h2.y); \
      h11.y = fmaf(w_, paa_, h11.y); h22.y = fmaf(w_, pbb_, h22.y); \
      h12.y = fmaf(w_, pab_, h12.y); } }

// vertical tap: slot index is a constant expression (P,D are literals)
#define VTAP(P,D) { \
    constexpr int s_ = (((P) - (D)) % 11 + 11) % 11; \
    const float wv_ = GW(D); \
    acc1[s_].x  = fmaf(wv_, h1.x,  acc1[s_].x);  acc1[s_].y  = fmaf(wv_, h1.y,  acc1[s_].y); \
    acc2[s_].x  = fmaf(wv_, h2.x,  acc2[s_].x);  acc2[s_].y  = fmaf(wv_, h2.y,  acc2[s_].y); \
    acc11[s_].x = fmaf(wv_, h11.x, acc11[s_].x); acc11[s_].y = fmaf(wv_, h11.y, acc11[s_].y); \
    acc22[s_].x = fmaf(wv_, h22.x, acc22[s_].x); acc22[s_].y = fmaf(wv_, h22.y, acc22[s_].y); \
    acc12[s_].x = fmaf(wv_, h12.x, acc12[s_].x); acc12[s_].y = fmaf(wv_, h12.y, acc12[s_].y); }

#define SSIMND(MU1,MU2,E11,E22,E12,NN,DD) { \
    const float m1s_=(MU1)*(MU1), m2s_=(MU2)*(MU2), m12_=(MU1)*(MU2); \
    const float v11_=(E11)-m1s_, v22_=(E22)-m2s_, v12_=(E12)-m12_; \
    NN = (2.f*m12_+C1)*(2.f*v12_+C2); \
    DD = (m1s_+m2s_+C1)*(v11_+v22_+C2); }

#define PHASE(P) if (ir < ir_end) { \
    const int buf_ = ir & 1; \
    *(float2*)&s1[buf_][col2] = ra; \
    *(float2*)&s2[buf_][col2] = rb; \
    __syncthreads(); \
    { const size_t nro_ = (size_t)min(ir + 1, H - 1) * W + col2; \
      ra = *(const float2*)(p1 + nro_); rb = *(const float2*)(p2 + nro_); } \
    float2 A[6], B[6]; \
    _Pragma("unroll") \
    for (int j_ = 0; j_ < 6; ++j_) { \
        A[j_] = *(const float2*)&s1[buf_][col2 + 2*j_]; \
        B[j_] = *(const float2*)&s2[buf_][col2 + 2*j_]; } \
    float2 h1=z2, h2=z2, h11=z2, h22=z2, h12=z2; \
    HPOS(0) HPOS(1) HPOS(2) HPOS(3) HPOS(4) HPOS(5) \
    HPOS(6) HPOS(7) HPOS(8) HPOS(9) HPOS(10) HPOS(11) \
    VTAP(P,0) VTAP(P,1) VTAP(P,2) VTAP(P,3) VTAP(P,4) VTAP(P,5) \
    VTAP(P,6) VTAP(P,7) VTAP(P,8) VTAP(P,9) VTAP(P,10) \
    { constexpr int cs_ = ((P) + 1) % 11; \
      const int orow_ = ir - 10; \
      if (orow_ >= r0 && orow_ < r1) { \
        float n0_, d0_, n1_, d1_; \
        SSIMND(acc1[cs_].x, acc2[cs_].x, acc11[cs_].x, acc22[cs_].x, acc12[cs_].x, n0_, d0_) \
        SSIMND(acc1[cs_].y, acc2[cs_].y, acc11[cs_].y, acc22[cs_].y, acc12[cs_].y, n1_, d1_) \
        n0_ = c0ok ? n0_ : 0.f;  d0_ = c0ok ? d0_ : 1.f; \
        n1_ = c1ok ? n1_ : 0.f;  d1_ = c1ok ? d1_ : 1.f; \
        sum += fmaf(n0_, d1_, n1_ * d0_) / (d0_ * d1_); } \
      acc1[cs_]=z2; acc2[cs_]=z2; acc11[cs_]=z2; acc22[cs_]=z2; acc12[cs_]=z2; } \
    ++ir; }

__global__ __launch_bounds__(256, 2)
void ssim_main(const float* __restrict__ img1, const float* __restrict__ img2,
               double* __restrict__ partials)
{
    __shared__ float s1[2][524];   // ping-pong staged row, x1; [512..521] zero pad
    __shared__ float s2[2][524];   // x2
    __shared__ float red[4];

    const int tid   = threadIdx.x;
    const int bid   = blockIdx.x;
    const int strip = bid % NS;
    const int plane = bid / NS;

    const int r0 = strip * SH;
    const int nrows = min(SH, OWID - r0);
    const int r1 = r0 + nrows;
    const int ir_end = r0 + nrows + 10;          // exact rows needed
    const int ngroups = (nrows + 20) / 11;

    const size_t pbase = (size_t)plane * (W * H);
    const float* __restrict__ p1 = img1 + pbase;
    const float* __restrict__ p2 = img2 + pbase;

    const int col2 = 2 * tid;
    const bool c0ok = (col2)     < OWID;
    const bool c1ok = (col2 + 1) < OWID;

    const float C1 = 4.0e-4f;    // (0.01*2)^2
    const float C2 = 3.6e-3f;    // (0.03*2)^2
    const float2 z2 = make_float2(0.f, 0.f);

    // zero the read-overrun pad (threads with col2+11 > 511 have invalid
    // outputs anyway, but reads must be finite)
    if (tid < 10) {
        s1[0][512 + tid] = 0.f; s1[1][512 + tid] = 0.f;
        s2[0][512 + tid] = 0.f; s2[1][512 + tid] = 0.f;
    }

    // rotating 11-slot float2 accumulators (all indices parse-time constants)
    float2 acc1[11], acc2[11], acc11[11], acc22[11], acc12[11];
#pragma unroll
    for (int i = 0; i < 11; ++i) {
        acc1[i]=z2; acc2[i]=z2; acc11[i]=z2; acc22[i]=z2; acc12[i]=z2;
    }

    float sum = 0.f;
    int ir = r0;

    // prefetch first row
    float2 ra, rb;
    {
        const size_t ro = (size_t)ir * W + col2;
        ra = *(const float2*)(p1 + ro);
        rb = *(const float2*)(p2 + ro);
    }

    for (int g = 0; g < ngroups; ++g) {
        PHASE(0) PHASE(1) PHASE(2) PHASE(3) PHASE(4) PHASE(5)
        PHASE(6) PHASE(7) PHASE(8) PHASE(9) PHASE(10)
    }

    // block reduction: per-wave shfl tree -> 4 partials -> thread 0
#pragma unroll
    for (int off = 32; off > 0; off >>= 1)
        sum += __shfl_down(sum, off, 64);
    if ((tid & 63) == 0) red[tid >> 6] = sum;
    __syncthreads();
    if (tid == 0)
        partials[bid] = (double)(red[0] + red[1] + red[2] + red[3]);
}

__global__ void ssim_final(const double* __restrict__ partials, float* __restrict__ out)
{
    __shared__ double sd[256];
    const int tid = threadIdx.x;
    double s = 0.0;
    for (int i = tid; i < NBLOCKS; i += 256) s += partials[i];
    sd[tid] = s;
    __syncthreads();
    for (int off = 128; off > 0; off >>= 1) {
        if (tid < off) sd[tid] += sd[tid + off];
        __syncthreads();
    }
    if (tid == 0) out[0] = 1.0f - (float)(sd[0] / NTOTAL);
}

extern "C" void kernel_launch(void* const* d_in, const int* in_sizes, int n_in,
                              void* d_out, int out_size, void* d_ws, size_t ws_size,
                              hipStream_t stream)
{
    const float* img1 = (const float*)d_in[0];
    const float* img2 = (const float*)d_in[1];
    float* out = (float*)d_out;
    double* partials = (double*)d_ws;   // NBLOCKS doubles = 6144 B

    ssim_main<<<NBLOCKS, 256, 0, stream>>>(img1, img2, partials);
    ssim_final<<<1, 256, 0, stream>>>(partials, out);
}